// Round 2
// baseline (501.635 us; speedup 1.0000x reference)
//
#include <hip/hip_runtime.h>

typedef unsigned short u16;
typedef short bf16x8 __attribute__((ext_vector_type(8)));
typedef float f32x4 __attribute__((ext_vector_type(4)));

#define MFMA16(a, b, c) __builtin_amdgcn_mfma_f32_16x16x32_bf16(a, b, c, 0, 0, 0)

static constexpr int L_ = 2048, B_ = 4, E_ = 1024, H_ = 16, HD_ = 64;
static constexpr int M_ = L_ * B_;              // 8192 rows for projections
static constexpr int BH_ = B_ * H_;             // 64 sequences
static constexpr size_t SEQSZ = (size_t)BH_ * L_ * HD_;  // 8388608 elems

__device__ __forceinline__ void gload16(const void* g, void* l) {
  __builtin_amdgcn_global_load_lds((const __attribute__((address_space(1))) void*)g,
                                   (__attribute__((address_space(3))) void*)l, 16, 0, 0);
}

__device__ __forceinline__ u16 f2bf(float f) {
  union { float f; unsigned u; } v; v.f = f;
  unsigned r = v.u + 0x7fffu + ((v.u >> 16) & 1u);   // RNE
  return (u16)(r >> 16);
}
__device__ __forceinline__ float bf2f(u16 h) {
  union { unsigned u; float f; } v; v.u = ((unsigned)h) << 16; return v.f;
}

__device__ __forceinline__ bf16x8 cvt8(float4 a, float4 b) {
  bf16x8 r;
  r[0] = (short)f2bf(a.x); r[1] = (short)f2bf(a.y);
  r[2] = (short)f2bf(a.z); r[3] = (short)f2bf(a.w);
  r[4] = (short)f2bf(b.x); r[5] = (short)f2bf(b.y);
  r[6] = (short)f2bf(b.z); r[7] = (short)f2bf(b.w);
  return r;
}

// ---------------------------------------------------------------------------
// QKV projection: C[M,N] = A[M,K] @ W[N,K]^T + bias.  A, W, bias fp32.
// z = blockIdx.z selects (q,k,v). Writes bf16: Q(scaled 1/8)/K as (BH,L,64),
// V transposed as (BH,64,L).
// ---------------------------------------------------------------------------
__global__ __launch_bounds__(256) void gemm_qkv(
    const float* __restrict__ Aq, const float* __restrict__ Ak, const float* __restrict__ Av,
    const float* __restrict__ W, const float* __restrict__ bias,
    u16* __restrict__ oq, u16* __restrict__ ok, u16* __restrict__ ov) {
  __shared__ __align__(16) u16 As[128][32];
  __shared__ __align__(16) u16 Bs[128][32];
  const int t = threadIdx.x, wave = t >> 6, lane = t & 63, quad = lane >> 4, l15 = lane & 15;
  const int n0 = blockIdx.x * 128, m0 = blockIdx.y * 128, z = blockIdx.z;
  const float* A = (z == 0) ? Aq : (z == 1 ? Ak : Av);
  const float* Wz = W + (size_t)z * E_ * E_;
  const float* bz = bias + z * E_;
  const int wm = (wave >> 1) * 64, wn = (wave & 1) * 64;

  const f32x4 vzero = {0.f, 0.f, 0.f, 0.f};
  f32x4 acc[4][4];
#pragma unroll
  for (int i = 0; i < 4; ++i)
#pragma unroll
    for (int j = 0; j < 4; ++j) acc[i][j] = vzero;

  for (int kk = 0; kk < E_; kk += 32) {
    // stage 128x32 fp32 tiles -> bf16 LDS, XOR part-swizzle p = pp ^ ((r>>1)&3)
#pragma unroll
    for (int i = 0; i < 2; ++i) {
      const int c = t + i * 256;               // chunk of 8 elems
      const int r = c >> 2, pp = c & 3, p = pp ^ ((r >> 1) & 3);
      const float* ga = A + (size_t)(m0 + r) * E_ + kk + p * 8;
      const float* gb = Wz + (size_t)(n0 + r) * E_ + kk + p * 8;
      const float4 a0 = *(const float4*)ga, a1 = *(const float4*)(ga + 4);
      const float4 b0 = *(const float4*)gb, b1 = *(const float4*)(gb + 4);
      *(bf16x8*)&As[r][pp * 8] = cvt8(a0, a1);
      *(bf16x8*)&Bs[r][pp * 8] = cvt8(b0, b1);
    }
    __syncthreads();
    bf16x8 af[4], bfr[4];
#pragma unroll
    for (int x = 0; x < 4; ++x) {
      const int ra = wm + x * 16 + l15;
      af[x] = *(const bf16x8*)&As[ra][(quad ^ ((ra >> 1) & 3)) * 8];
      const int rb = wn + x * 16 + l15;
      bfr[x] = *(const bf16x8*)&Bs[rb][(quad ^ ((rb >> 1) & 3)) * 8];
    }
#pragma unroll
    for (int mi = 0; mi < 4; ++mi)
#pragma unroll
      for (int ni = 0; ni < 4; ++ni)
        acc[mi][ni] = MFMA16(af[mi], bfr[ni], acc[mi][ni]);
    __syncthreads();
  }

  // epilogue: C row = quad*4+reg, col = lane&15 (verified m89/m91 layout)
#pragma unroll
  for (int ni = 0; ni < 4; ++ni) {
    const int n = n0 + wn + ni * 16 + l15;
    const float bv = bz[n];
#pragma unroll
    for (int mi = 0; mi < 4; ++mi) {
#pragma unroll
      for (int r = 0; r < 4; ++r) {
        const int m = m0 + wm + mi * 16 + quad * 4 + r;
        const float val = acc[mi][ni][r] + bv;
        const int l = m >> 2, bb = m & 3, h = n >> 6, d = n & 63;
        const int s = bb * H_ + h;
        if (z == 0) {
          oq[(size_t)s * (L_ * HD_) + (size_t)l * HD_ + d] = f2bf(val * 0.125f);
        } else if (z == 1) {
          ok[(size_t)s * (L_ * HD_) + (size_t)l * HD_ + d] = f2bf(val);
        } else {
          ov[((size_t)s * HD_ + d) * L_ + l] = f2bf(val);
        }
      }
    }
  }
}

// ---------------------------------------------------------------------------
// Out projection: out[M,N] = A[M,K](bf16) @ W[N,K]^T(fp32) + bias(fp32), fp32 out.
// A staged via global_load_lds (fast path), W convert-staged.
// ---------------------------------------------------------------------------
__global__ __launch_bounds__(256) void gemm_out(
    const u16* __restrict__ A, const float* __restrict__ W, const float* __restrict__ bias,
    float* __restrict__ out) {
  __shared__ __align__(16) u16 As[128][32];
  __shared__ __align__(16) u16 Bs[128][32];
  const int t = threadIdx.x, wave = t >> 6, lane = t & 63, quad = lane >> 4, l15 = lane & 15;
  const int n0 = blockIdx.x * 128, m0 = blockIdx.y * 128;
  const int wm = (wave >> 1) * 64, wn = (wave & 1) * 64;

  const f32x4 vzero = {0.f, 0.f, 0.f, 0.f};
  f32x4 acc[4][4];
#pragma unroll
  for (int i = 0; i < 4; ++i)
#pragma unroll
    for (int j = 0; j < 4; ++j) acc[i][j] = vzero;

  for (int kk = 0; kk < E_; kk += 32) {
    // A (bf16): async direct-to-LDS, 2 chunks per thread
#pragma unroll
    for (int i = 0; i < 2; ++i) {
      const int c0 = (i * 4 + wave) * 64;
      const int c = c0 + lane;
      const int r = c >> 2;
      const int p = (c & 3) ^ ((r >> 1) & 3);
      gload16(A + (size_t)(m0 + r) * E_ + kk + p * 8, (u16*)As + c0 * 8);
    }
    // W (fp32): load + convert + ds_write (overlaps with async A loads)
#pragma unroll
    for (int i = 0; i < 2; ++i) {
      const int c = t + i * 256;
      const int r = c >> 2, pp = c & 3, p = pp ^ ((r >> 1) & 3);
      const float* gb = W + (size_t)(n0 + r) * E_ + kk + p * 8;
      const float4 b0 = *(const float4*)gb, b1 = *(const float4*)(gb + 4);
      *(bf16x8*)&Bs[r][pp * 8] = cvt8(b0, b1);
    }
    __syncthreads();
    bf16x8 af[4], bfr[4];
#pragma unroll
    for (int x = 0; x < 4; ++x) {
      const int ra = wm + x * 16 + l15;
      af[x] = *(const bf16x8*)&As[ra][(quad ^ ((ra >> 1) & 3)) * 8];
      const int rb = wn + x * 16 + l15;
      bfr[x] = *(const bf16x8*)&Bs[rb][(quad ^ ((rb >> 1) & 3)) * 8];
    }
#pragma unroll
    for (int mi = 0; mi < 4; ++mi)
#pragma unroll
      for (int ni = 0; ni < 4; ++ni)
        acc[mi][ni] = MFMA16(af[mi], bfr[ni], acc[mi][ni]);
    __syncthreads();
  }

#pragma unroll
  for (int ni = 0; ni < 4; ++ni) {
    const int n = n0 + wn + ni * 16 + l15;
    const float bv = bias[n];
#pragma unroll
    for (int mi = 0; mi < 4; ++mi) {
#pragma unroll
      for (int r = 0; r < 4; ++r) {
        const int m = m0 + wm + mi * 16 + quad * 4 + r;
        out[(size_t)m * E_ + n] = acc[mi][ni][r] + bv;
      }
    }
  }
}

// ---------------------------------------------------------------------------
// Flash attention: Q pre-scaled (BH,L,64), K (BH,L,64), Vt (BH,64,L), all bf16.
// One WG per 64 q-rows; 4 waves x 16 rows; K-tiles of 128.
// ---------------------------------------------------------------------------
__global__ __launch_bounds__(256) void attn_fused(
    const u16* __restrict__ Q, const u16* __restrict__ K,
    const u16* __restrict__ Vt, u16* __restrict__ O) {
  __shared__ __align__(16) u16 Ks[128][64];    // [j][d], part-swizzled by (r&7)
  __shared__ __align__(16) u16 Vs[64][128];    // [d][j], part-swizzled by (r&15)
  __shared__ __align__(16) u16 Ps[4][16][136]; // per-wave P tile, padded stride
  const int t = threadIdx.x, wave = t >> 6, lane = t & 63, quad = lane >> 4, l15 = lane & 15;
  const int bh = blockIdx.y, q0 = blockIdx.x * 64;
  const u16* Qb = Q + (size_t)bh * L_ * HD_;
  const u16* Kb = K + (size_t)bh * L_ * HD_;
  const u16* Vb = Vt + (size_t)bh * HD_ * L_;

  // Q fragments in registers for whole kernel: A[m=lane&15][k=quad*8+j]
  const int qrow = q0 + wave * 16 + l15;
  const bf16x8 qf0 = *(const bf16x8*)(Qb + (size_t)qrow * HD_ + quad * 8);
  const bf16x8 qf1 = *(const bf16x8*)(Qb + (size_t)qrow * HD_ + 32 + quad * 8);

  const f32x4 vzero = {0.f, 0.f, 0.f, 0.f};
  float run_m[4], run_l[4];
  f32x4 oacc[4];
#pragma unroll
  for (int r = 0; r < 4; ++r) { run_m[r] = -3.0e38f; run_l[r] = 0.f; }
#pragma unroll
  for (int di = 0; di < 4; ++di) oacc[di] = vzero;

  for (int j0 = 0; j0 < L_; j0 += 128) {
#pragma unroll
    for (int i = 0; i < 4; ++i) {
      const int c0 = (i * 4 + wave) * 64;
      const int c = c0 + lane;
      { // K tile: 128 rows x 64 elems, 8 chunks/row
        const int r = c >> 3, p = (c & 7) ^ (r & 7);
        gload16(Kb + (size_t)(j0 + r) * HD_ + p * 8, (u16*)Ks + c0 * 8);
      }
      { // V tile: 64 rows x 128 elems, 16 chunks/row
        const int r = c >> 4, p = (c & 15) ^ (r & 15);
        gload16(Vb + (size_t)r * L_ + j0 + p * 8, (u16*)Vs + c0 * 8);
      }
    }
    __syncthreads();

    // S = Q K^T : 8 n-tiles x 2 k-steps
    f32x4 sacc[8];
#pragma unroll
    for (int ni = 0; ni < 8; ++ni) sacc[ni] = vzero;
#pragma unroll
    for (int ni = 0; ni < 8; ++ni) {
      const int row = ni * 16 + l15;
      const bf16x8 k0 = *(const bf16x8*)&Ks[row][(quad ^ (row & 7)) * 8];
      const bf16x8 k1 = *(const bf16x8*)&Ks[row][((4 + quad) ^ (row & 7)) * 8];
      sacc[ni] = MFMA16(qf0, k0, sacc[ni]);
      sacc[ni] = MFMA16(qf1, k1, sacc[ni]);
    }

    // online softmax; row = quad*4 + r, its 16 cols live in the quad's 16 lanes
    float alpha[4], rs[4];
#pragma unroll
    for (int r = 0; r < 4; ++r) {
      float mx = sacc[0][r];
#pragma unroll
      for (int ni = 1; ni < 8; ++ni) mx = fmaxf(mx, sacc[ni][r]);
#pragma unroll
      for (int s = 1; s < 16; s <<= 1) mx = fmaxf(mx, __shfl_xor(mx, s));
      const float nm = fmaxf(run_m[r], mx);
      alpha[r] = __expf(run_m[r] - nm);
      run_m[r] = nm;
      rs[r] = 0.f;
    }
#pragma unroll
    for (int ni = 0; ni < 8; ++ni) {
#pragma unroll
      for (int r = 0; r < 4; ++r) {
        const u16 pb = f2bf(__expf(sacc[ni][r] - run_m[r]));
        Ps[wave][quad * 4 + r][ni * 16 + l15] = pb;
        rs[r] += bf2f(pb);
      }
    }
#pragma unroll
    for (int r = 0; r < 4; ++r) {
      float s = rs[r];
#pragma unroll
      for (int sh = 1; sh < 16; sh <<= 1) s += __shfl_xor(s, sh);
      run_l[r] = run_l[r] * alpha[r] + s;
    }
#pragma unroll
    for (int di = 0; di < 4; ++di)
#pragma unroll
      for (int r = 0; r < 4; ++r) oacc[di][r] *= alpha[r];

    // O += P V : P via per-wave LDS round-trip (C-layout -> A-layout)
#pragma unroll
    for (int s2 = 0; s2 < 4; ++s2) {
      const bf16x8 pa = *(const bf16x8*)&Ps[wave][l15][s2 * 32 + quad * 8];
#pragma unroll
      for (int di = 0; di < 4; ++di) {
        const int row = di * 16 + l15;
        const bf16x8 vb = *(const bf16x8*)&Vs[row][((s2 * 4 + quad) ^ (row & 15)) * 8];
        oacc[di] = MFMA16(pa, vb, oacc[di]);
      }
    }
    __syncthreads();
  }

  // epilogue: write O (bf16) directly in (L, B, E) layout for the out-proj GEMM
  const int b = bh >> 4, h = bh & 15;
#pragma unroll
  for (int r = 0; r < 4; ++r) {
    const float inv = 1.f / run_l[r];
    const int l = q0 + wave * 16 + quad * 4 + r;
#pragma unroll
    for (int di = 0; di < 4; ++di) {
      const int e = h * 64 + di * 16 + l15;
      O[((size_t)l * B_ + b) * E_ + e] = f2bf(oacc[di][r] * inv);
    }
  }
}

extern "C" void kernel_launch(void* const* d_in, const int* in_sizes, int n_in,
                              void* d_out, int out_size, void* d_ws, size_t ws_size,
                              hipStream_t stream) {
  const float* q = (const float*)d_in[0];
  const float* k = (const float*)d_in[1];
  const float* v = (const float*)d_in[2];
  const float* w = (const float*)d_in[3];      // (3072, 1024) fp32
  const float* bqkv = (const float*)d_in[4];   // (3072,) fp32
  const float* ow = (const float*)d_in[5];     // (1024, 1024) fp32
  const float* ob = (const float*)d_in[6];     // (1024,) fp32

  u16* qs = (u16*)d_ws;          // (BH, L, 64) bf16, pre-scaled by 1/8
  u16* ks = qs + SEQSZ;          // (BH, L, 64) bf16
  u16* vt = ks + SEQSZ;          // (BH, 64, L) bf16
  u16* obuf = vt + SEQSZ;        // (L*B, E) bf16 attention output

  gemm_qkv<<<dim3(E_ / 128, M_ / 128, 3), 256, 0, stream>>>(q, k, v, w, bqkv, qs, ks, vt);
  attn_fused<<<dim3(L_ / 64, BH_), 256, 0, stream>>>(qs, ks, vt, obuf);
  gemm_out<<<dim3(E_ / 128, M_ / 128), 256, 0, stream>>>(obuf, ow, ob, (float*)d_out);
}